// Round 1
// 207.196 us; speedup vs baseline: 1.0210x; 1.0210x over previous
//
#include <hip/hip_runtime.h>
#include <math.h>

#define TOKENS 16384
#define DIM    2048
#define NE     64
#define TB     32            // tokens per block (one 32-row MFMA tile)
#define KG     8             // k-split across the block's 8 waves
#define KW     (DIM / KG)    // 256 k per wave
#define NCH    (KW / 16)     // 16 chunks of 16 k

typedef _Float16 f16x8 __attribute__((ext_vector_type(8)));
typedef float    f32x16 __attribute__((ext_vector_type(16)));

// ---------- Kernel A: pack W fp32 -> split-f16 B-fragment layout ----------
// wp layout (f16 units): ((c*2 + eg)*2 + hl)*512 + lane*8 + j
//   c   = k-chunk (16 k), 0..127      eg = expert half (32 experts)
//   hl  = 0 hi / 1 lo residual        lane: e = eg*32+(lane&31), k = c*16+(lane>>5)*8+j
__global__ __launch_bounds__(256) void wpack_kernel(const float* __restrict__ W,
                                                    _Float16* __restrict__ wp) {
    const int g  = blockIdx.x * 256 + threadIdx.x;   // 16384 threads
    const int c  = g >> 7;
    const int eg = (g >> 6) & 1;
    const int l  = g & 63;
    const int e  = eg * 32 + (l & 31);
    const int k0 = c * 16 + (l >> 5) * 8;
    const float* src = W + (size_t)e * DIM + k0;
    float4 a = *(const float4*)src;
    float4 bq = *(const float4*)(src + 4);
    const float* pa = (const float*)&a;
    const float* pb = (const float*)&bq;
    f16x8 h, lo;
    #pragma unroll
    for (int j = 0; j < 4; ++j) {
        _Float16 h1 = (_Float16)pa[j];
        h[j] = h1; lo[j] = (_Float16)(pa[j] - (float)h1);
        _Float16 h2 = (_Float16)pb[j];
        h[4 + j] = h2; lo[4 + j] = (_Float16)(pb[j] - (float)h2);
    }
    _Float16* dst = wp + ((size_t)(c * 2 + eg) * 2) * 512 + l * 8;
    *(f16x8*)dst = h;
    *(f16x8*)(dst + 512) = lo;
}

// ---------- Kernel B: barrier-free split-f16 MFMA GEMM + top-2 + softmax ----------
// 512 thr = 8 waves, wave = kg. Wave computes 32 tok x 64 exp over its 256-k slice,
// A-frags straight from global x, B-frags from packed wp. One barrier at epilogue.
// KG=8 doubles resident waves/SIMD (2 -> 4) to hide the ~900-cyc HBM latency of the
// per-lane strided x loads (prefetch depth 2 gives only ~220 cyc tolerance per wave).
__global__ __launch_bounds__(512, 4) void router_kernel(const float* __restrict__ x,
                                                        const _Float16* __restrict__ wp,
                                                        const float* __restrict__ b,
                                                        float* __restrict__ out) {
    __shared__ __align__(16) float lds[KG * TB * NE];   // 64 KB: 8 partial zones

    const int tid  = threadIdx.x;
    const int kg   = tid >> 6;
    const int lane = tid & 63;
    const int t0   = blockIdx.x * TB;
    const int m    = lane & 31;        // token row within tile
    const int ko   = lane >> 5;        // k-octet half

    const float* xp = x + (size_t)(t0 + m) * DIM + kg * KW + ko * 8;
    const _Float16* wpb = wp + (size_t)kg * NCH * 2048;   // chunk stride = 2048 f16

    f32x16 acc0, acc1;
    #pragma unroll
    for (int i = 0; i < 16; ++i) { acc0[i] = 0.0f; acc1[i] = 0.0f; }

    float4 xs0[2], xs1[2];
    f16x8  bs[2][4];

    auto ld = [&](int c, int sl) {
        const float* s = xp + c * 16;
        xs0[sl] = *(const float4*)s;
        xs1[sl] = *(const float4*)(s + 4);
        const _Float16* wb = wpb + (size_t)c * 2048 + lane * 8;
        bs[sl][0] = *(const f16x8*)(wb);           // eg0 hi
        bs[sl][1] = *(const f16x8*)(wb + 512);     // eg0 lo
        bs[sl][2] = *(const f16x8*)(wb + 1024);    // eg1 hi
        bs[sl][3] = *(const f16x8*)(wb + 1536);    // eg1 lo
    };

    ld(0, 0);
    ld(1, 1);

    #pragma unroll 2
    for (int c = 0; c < NCH; ++c) {
        const int sl = c & 1;
        f16x8 ah, al;
        {
            const float* p0 = (const float*)&xs0[sl];
            const float* p1 = (const float*)&xs1[sl];
            #pragma unroll
            for (int j = 0; j < 4; ++j) {
                _Float16 h1 = (_Float16)p0[j];
                ah[j] = h1; al[j] = (_Float16)(p0[j] - (float)h1);
                _Float16 h2 = (_Float16)p1[j];
                ah[4 + j] = h2; al[4 + j] = (_Float16)(p1[j] - (float)h2);
            }
        }
        const f16x8 b0h = bs[sl][0], b0l = bs[sl][1];
        const f16x8 b1h = bs[sl][2], b1l = bs[sl][3];

        acc0 = __builtin_amdgcn_mfma_f32_32x32x16_f16(ah, b0h, acc0, 0, 0, 0);
        acc1 = __builtin_amdgcn_mfma_f32_32x32x16_f16(ah, b1h, acc1, 0, 0, 0);
        acc0 = __builtin_amdgcn_mfma_f32_32x32x16_f16(ah, b0l, acc0, 0, 0, 0);
        acc1 = __builtin_amdgcn_mfma_f32_32x32x16_f16(ah, b1l, acc1, 0, 0, 0);
        acc0 = __builtin_amdgcn_mfma_f32_32x32x16_f16(al, b0h, acc0, 0, 0, 0);
        acc1 = __builtin_amdgcn_mfma_f32_32x32x16_f16(al, b1h, acc1, 0, 0, 0);

        if (c + 2 < NCH) ld(c + 2, sl);
    }

    // ---- partials -> LDS zone kg (row-major 32 x 64) ----
    float* zone = lds + kg * (TB * NE);
    #pragma unroll
    for (int r = 0; r < 16; ++r) {
        const int row = (r & 3) + 8 * (r >> 2) + 4 * ko;   // C/D layout (verified)
        zone[row * 64 + m]      = acc0[r];
        zone[row * 64 + 32 + m] = acc1[r];
    }
    __syncthreads();

    // ---- block-wide reduce of 8 zones + bias; logits to global; stage for top-2 ----
    float* logits_out = out + (size_t)TOKENS * 4;
    {
        const int row = tid >> 4;          // 0..31
        const int c4  = (tid & 15) * 4;    // col start (one float4 per thread)
        const int base = row * 64 + c4;
        float4 s0 = *(float4*)&lds[base];
        #pragma unroll
        for (int z = 1; z < KG; ++z) {
            float4 a0 = *(float4*)&lds[z * 2048 + base];
            s0.x += a0.x; s0.y += a0.y; s0.z += a0.z; s0.w += a0.w;
        }
        float4 bv0 = *(const float4*)&b[c4];
        s0.x += bv0.x; s0.y += bv0.y; s0.z += bv0.z; s0.w += bv0.w;
        *(float4*)&lds[base] = s0;     // zone0 in-place (safe: same thread's slot)
        *(float4*)&logits_out[(size_t)(t0 + row) * 64 + c4] = s0;
    }
    __syncthreads();

    // ---- top-2 + softmax: wave kg handles tokens kg*4 .. kg*4+3 ----
    float* idxf = out + (size_t)TOKENS * 2;
    for (int i = 0; i < 4; ++i) {
        const int t = kg * 4 + i;
        const float v = lds[t * 64 + lane];

        float v1 = v; int i1 = lane;
        #pragma unroll
        for (int off = 32; off >= 1; off >>= 1) {
            float ov = __shfl_xor(v1, off, 64);
            int   oi = __shfl_xor(i1, off, 64);
            if (ov > v1 || (ov == v1 && oi < i1)) { v1 = ov; i1 = oi; }
        }
        float vm = (lane == i1) ? -INFINITY : v;
        float v2 = vm; int i2 = lane;
        #pragma unroll
        for (int off = 32; off >= 1; off >>= 1) {
            float ov = __shfl_xor(v2, off, 64);
            int   oi = __shfl_xor(i2, off, 64);
            if (ov > v2 || (ov == v2 && oi < i2)) { v2 = ov; i2 = oi; }
        }

        if (lane == 0) {
            const int tok = t0 + t;
            float e1 = expf(v2 - v1);          // v1 >= v2: stable
            float sden = 1.0f + e1;
            *(float2*)&out[(size_t)tok * 2]  = make_float2(1.0f / sden, e1 / sden);
            *(float2*)&idxf[(size_t)tok * 2] = make_float2((float)i1, (float)i2);
        }
    }
}

extern "C" void kernel_launch(void* const* d_in, const int* in_sizes, int n_in,
                              void* d_out, int out_size, void* d_ws, size_t ws_size,
                              hipStream_t stream) {
    const float* x = (const float*)d_in[0];
    const float* W = (const float*)d_in[1];
    const float* b = (const float*)d_in[2];
    float* out = (float*)d_out;
    _Float16* wp = (_Float16*)d_ws;    // 128*2*2*512 f16 = 512 KB packed fragments

    wpack_kernel<<<64, 256, 0, stream>>>(W, wp);
    router_kernel<<<TOKENS / TB, 512, 0, stream>>>(x, wp, b, out);
}

// Round 2
// 199.966 us; speedup vs baseline: 1.0579x; 1.0362x over previous
//
#include <hip/hip_runtime.h>
#include <math.h>

#define TOKENS 16384
#define DIM    2048
#define NE     64
#define TB     32            // tokens per block (one 32-row MFMA tile)
#define KG     8             // k-split across the block's 8 waves
#define BK     256           // k staged per step (32 rows x 256 f32 = 32 KB)
#define NSTEP  (DIM / BK)    // 8 steps; per wave per step: 32 k = 2 chunks of 16

typedef _Float16 f16x8 __attribute__((ext_vector_type(8)));
typedef float    f32x16 __attribute__((ext_vector_type(16)));

// ---------- Kernel A: pack W fp32 -> split-f16 B-fragment layout ----------
// wp layout (f16 units): ((c*2 + eg)*2 + hl)*512 + lane*8 + j
//   c   = k-chunk (16 k), 0..127      eg = expert half (32 experts)
//   hl  = 0 hi / 1 lo residual        lane: e = eg*32+(lane&31), k = c*16+(lane>>5)*8+j
__global__ __launch_bounds__(256) void wpack_kernel(const float* __restrict__ W,
                                                    _Float16* __restrict__ wp) {
    const int g  = blockIdx.x * 256 + threadIdx.x;   // 16384 threads
    const int c  = g >> 7;
    const int eg = (g >> 6) & 1;
    const int l  = g & 63;
    const int e  = eg * 32 + (l & 31);
    const int k0 = c * 16 + (l >> 5) * 8;
    const float* src = W + (size_t)e * DIM + k0;
    float4 a = *(const float4*)src;
    float4 bq = *(const float4*)(src + 4);
    const float* pa = (const float*)&a;
    const float* pb = (const float*)&bq;
    f16x8 h, lo;
    #pragma unroll
    for (int j = 0; j < 4; ++j) {
        _Float16 h1 = (_Float16)pa[j];
        h[j] = h1; lo[j] = (_Float16)(pa[j] - (float)h1);
        _Float16 h2 = (_Float16)pb[j];
        h[4 + j] = h2; lo[4 + j] = (_Float16)(pb[j] - (float)h2);
    }
    _Float16* dst = wp + ((size_t)(c * 2 + eg) * 2) * 512 + l * 8;
    *(f16x8*)dst = h;
    *(f16x8*)(dst + 512) = lo;
}

// ---------- Kernel B: LDS-staged split-f16 MFMA GEMM + top-2 + softmax ----------
// x is staged through LDS so global reads are contiguous 1KB wave bursts
// (the direct per-lane fragment loads were 64B-granular scatter over 32 rows
//  -> ~2.9 TB/s effective HBM; staging restores long DRAM streams).
// Staging uses global_load_lds w=16 with LINEAR LDS dest + PRE-SWIZZLED global
// source (granule = lane ^ row); fragment ds_read_b128 applies the same XOR
// (slot = g ^ row) -> bank-conflict-free (else 32-way: rows are 1KB apart).
// 8 waves k-split; one barrier per step; epilogue zones overlay stage buffers.
__global__ __launch_bounds__(512, 4) void router_kernel(const float* __restrict__ x,
                                                        const _Float16* __restrict__ wp,
                                                        const float* __restrict__ b,
                                                        float* __restrict__ out) {
    __shared__ __align__(16) float lds[16384];   // 64 KB: 2x32KB stage bufs, reused as 8 zones

    const int tid  = threadIdx.x;
    const int kg   = tid >> 6;
    const int lane = tid & 63;
    const int t0   = blockIdx.x * TB;
    const int m    = lane & 31;        // token row within tile (frag row)
    const int ko   = lane >> 5;        // k-octet half

    // ---- staging: wave kg stages rows kg*4..kg*4+3; 1 instr = 1 row = 1KB burst ----
    const float* xbase = x + (size_t)t0 * DIM;
    auto stage = [&](int s, int bsel) {
        #pragma unroll
        for (int i = 0; i < 4; ++i) {
            const int r = kg * 4 + i;
            // global source pre-swizzled so LDS slot g holds global granule g^r
            const float* src = xbase + (size_t)r * DIM + s * BK + ((lane ^ r) << 2);
            float* dst = lds + bsel * 8192 + r * 256;   // wave-uniform; HW adds lane*16B
            __builtin_amdgcn_global_load_lds(
                (const __attribute__((address_space(1))) void*)src,
                (__attribute__((address_space(3))) void*)dst,
                16, 0, 0);
        }
    };

    // ---- precomputed swizzled ds_read byte offsets (constant across steps) ----
    int roff[2][2];
    #pragma unroll
    for (int cc = 0; cc < 2; ++cc)
        #pragma unroll
        for (int q = 0; q < 2; ++q) {
            const int g = kg * 8 + cc * 4 + ko * 2 + q;   // step-local granule
            roff[cc][q] = m * 1024 + ((g ^ m) << 4);
        }

    // ---- wp register pipeline (L2-resident, coalesced) ----
    const _Float16* wpl = wp + lane * 8;
    f16x8 bs[2][4];
    auto wld = [&](int n, int sl) {
        const int C = ((n >> 1) << 4) + (kg << 1) + (n & 1);   // global chunk id
        const _Float16* wb = wpl + (size_t)C * 2048;
        bs[sl][0] = *(const f16x8*)(wb);           // eg0 hi
        bs[sl][1] = *(const f16x8*)(wb + 512);     // eg0 lo
        bs[sl][2] = *(const f16x8*)(wb + 1024);    // eg1 hi
        bs[sl][3] = *(const f16x8*)(wb + 1536);    // eg1 lo
    };

    f32x16 acc0, acc1;
    #pragma unroll
    for (int i = 0; i < 16; ++i) { acc0[i] = 0.0f; acc1[i] = 0.0f; }

    stage(0, 0);
    wld(0, 0); wld(1, 1);
    __syncthreads();

    #pragma unroll 2
    for (int s = 0; s < NSTEP; ++s) {
        const int bsel = s & 1;
        if (s + 1 < NSTEP) stage(s + 1, bsel ^ 1);   // prefetch next tile into other buf

        const char* lb = (const char*)lds + bsel * 32768;
        float4 xv[2][2];
        #pragma unroll
        for (int cc = 0; cc < 2; ++cc) {
            xv[cc][0] = *(const float4*)(lb + roff[cc][0]);
            xv[cc][1] = *(const float4*)(lb + roff[cc][1]);
        }

        #pragma unroll
        for (int cc = 0; cc < 2; ++cc) {
            f16x8 ah, al;
            const float* p0 = (const float*)&xv[cc][0];
            const float* p1 = (const float*)&xv[cc][1];
            #pragma unroll
            for (int j = 0; j < 4; ++j) {
                _Float16 h1 = (_Float16)p0[j];
                ah[j] = h1; al[j] = (_Float16)(p0[j] - (float)h1);
                _Float16 h2 = (_Float16)p1[j];
                ah[4 + j] = h2; al[4 + j] = (_Float16)(p1[j] - (float)h2);
            }
            const f16x8 b0h = bs[cc][0], b0l = bs[cc][1];
            const f16x8 b1h = bs[cc][2], b1l = bs[cc][3];

            acc0 = __builtin_amdgcn_mfma_f32_32x32x16_f16(ah, b0h, acc0, 0, 0, 0);
            acc1 = __builtin_amdgcn_mfma_f32_32x32x16_f16(ah, b1h, acc1, 0, 0, 0);
            acc0 = __builtin_amdgcn_mfma_f32_32x32x16_f16(ah, b0l, acc0, 0, 0, 0);
            acc1 = __builtin_amdgcn_mfma_f32_32x32x16_f16(ah, b1l, acc1, 0, 0, 0);
            acc0 = __builtin_amdgcn_mfma_f32_32x32x16_f16(al, b0h, acc0, 0, 0, 0);
            acc1 = __builtin_amdgcn_mfma_f32_32x32x16_f16(al, b1h, acc1, 0, 0, 0);

            const int n = s * 2 + cc;
            if (n + 2 < 16) wld(n + 2, cc);          // refill bs[cc] for 2 chunks ahead
        }
        __syncthreads();   // stage(s+1) complete; reads of buf[bsel] done before overwrite
    }

    // ---- partials -> LDS zone kg (row-major 32 x 64); overlays stage buffers ----
    float* zone = lds + kg * (TB * NE);
    #pragma unroll
    for (int r = 0; r < 16; ++r) {
        const int row = (r & 3) + 8 * (r >> 2) + 4 * ko;   // C/D layout (verified)
        zone[row * 64 + m]      = acc0[r];
        zone[row * 64 + 32 + m] = acc1[r];
    }
    __syncthreads();

    // ---- block-wide reduce of 8 zones + bias; logits to global; stage for top-2 ----
    float* logits_out = out + (size_t)TOKENS * 4;
    {
        const int row = tid >> 4;          // 0..31
        const int c4  = (tid & 15) * 4;    // col start (one float4 per thread)
        const int base = row * 64 + c4;
        float4 s0 = *(float4*)&lds[base];
        #pragma unroll
        for (int z = 1; z < KG; ++z) {
            float4 a0 = *(float4*)&lds[z * 2048 + base];
            s0.x += a0.x; s0.y += a0.y; s0.z += a0.z; s0.w += a0.w;
        }
        float4 bv0 = *(const float4*)&b[c4];
        s0.x += bv0.x; s0.y += bv0.y; s0.z += bv0.z; s0.w += bv0.w;
        *(float4*)&lds[base] = s0;     // zone0 in-place (safe: same thread's slot)
        *(float4*)&logits_out[(size_t)(t0 + row) * 64 + c4] = s0;
    }
    __syncthreads();

    // ---- top-2 + softmax: wave kg handles tokens kg*4 .. kg*4+3 ----
    float* idxf = out + (size_t)TOKENS * 2;
    for (int i = 0; i < 4; ++i) {
        const int t = kg * 4 + i;
        const float v = lds[t * 64 + lane];

        float v1 = v; int i1 = lane;
        #pragma unroll
        for (int off = 32; off >= 1; off >>= 1) {
            float ov = __shfl_xor(v1, off, 64);
            int   oi = __shfl_xor(i1, off, 64);
            if (ov > v1 || (ov == v1 && oi < i1)) { v1 = ov; i1 = oi; }
        }
        float vm = (lane == i1) ? -INFINITY : v;
        float v2 = vm; int i2 = lane;
        #pragma unroll
        for (int off = 32; off >= 1; off >>= 1) {
            float ov = __shfl_xor(v2, off, 64);
            int   oi = __shfl_xor(i2, off, 64);
            if (ov > v2 || (ov == v2 && oi < i2)) { v2 = ov; i2 = oi; }
        }

        if (lane == 0) {
            const int tok = t0 + t;
            float e1 = expf(v2 - v1);          // v1 >= v2: stable
            float sden = 1.0f + e1;
            *(float2*)&out[(size_t)tok * 2]  = make_float2(1.0f / sden, e1 / sden);
            *(float2*)&idxf[(size_t)tok * 2] = make_float2((float)i1, (float)i2);
        }
    }
}

extern "C" void kernel_launch(void* const* d_in, const int* in_sizes, int n_in,
                              void* d_out, int out_size, void* d_ws, size_t ws_size,
                              hipStream_t stream) {
    const float* x = (const float*)d_in[0];
    const float* W = (const float*)d_in[1];
    const float* b = (const float*)d_in[2];
    float* out = (float*)d_out;
    _Float16* wp = (_Float16*)d_ws;    // 128*2*2*512 f16 = 512 KB packed fragments

    wpack_kernel<<<64, 256, 0, stream>>>(W, wp);
    router_kernel<<<TOKENS / TB, 512, 0, stream>>>(x, wp, b, out);
}

// Round 3
// 199.053 us; speedup vs baseline: 1.0627x; 1.0046x over previous
//
#include <hip/hip_runtime.h>
#include <math.h>

#define TOKENS 16384
#define DIM    2048
#define NE     64
#define TB     32            // tokens per block (one 32-row MFMA tile)
#define KG     8             // k-split across the block's 8 waves
#define BK     128           // k staged per step (32 rows x 128 f32 = 16 KB buffer)
#define NSTEP  (DIM / BK)    // 16 steps; per wave per step: 1 chunk of 16 k

typedef _Float16 f16x8 __attribute__((ext_vector_type(8)));
typedef float    f32x16 __attribute__((ext_vector_type(16)));

// ---------- Kernel A: pack W fp32 -> split-f16 B-fragment layout ----------
// wp layout (f16 units): ((c*2 + eg)*2 + hl)*512 + lane*8 + j
//   c   = k-chunk (16 k), 0..127      eg = expert half (32 experts)
//   hl  = 0 hi / 1 lo residual        lane: e = eg*32+(lane&31), k = c*16+(lane>>5)*8+j
__global__ __launch_bounds__(256) void wpack_kernel(const float* __restrict__ W,
                                                    _Float16* __restrict__ wp) {
    const int g  = blockIdx.x * 256 + threadIdx.x;   // 16384 threads
    const int c  = g >> 7;
    const int eg = (g >> 6) & 1;
    const int l  = g & 63;
    const int e  = eg * 32 + (l & 31);
    const int k0 = c * 16 + (l >> 5) * 8;
    const float* src = W + (size_t)e * DIM + k0;
    float4 a = *(const float4*)src;
    float4 bq = *(const float4*)(src + 4);
    const float* pa = (const float*)&a;
    const float* pb = (const float*)&bq;
    f16x8 h, lo;
    #pragma unroll
    for (int j = 0; j < 4; ++j) {
        _Float16 h1 = (_Float16)pa[j];
        h[j] = h1; lo[j] = (_Float16)(pa[j] - (float)h1);
        _Float16 h2 = (_Float16)pb[j];
        h[4 + j] = h2; lo[4 + j] = (_Float16)(pb[j] - (float)h2);
    }
    _Float16* dst = wp + ((size_t)(c * 2 + eg) * 2) * 512 + l * 8;
    *(f16x8*)dst = h;
    *(f16x8*)(dst + 512) = lo;
}

// ---------- Kernel B: deep-pipelined LDS-staged split-f16 MFMA GEMM ----------
// T3+T4 structure: 4 stage buffers (depth-3 prefetch), counted s_waitcnt vmcnt(N)
// + raw s_barrier per step — never drain vmcnt to 0 in the main loop.
// (__syncthreads' vmcnt(0) drain was the R2 bottleneck: 5 us/step bulk-sync.)
// x staged via global_load_lds w=16: 2 instrs/wave/step, each 2 rows x 512B
// contiguous bursts. Swizzle slot = g ^ (row&7) applied on BOTH the pre-swizzled
// global source and the ds_read offsets (same involution) -> conflict-free reads.
__global__ __launch_bounds__(512, 4) void router_kernel(const float* __restrict__ x,
                                                        const _Float16* __restrict__ wp,
                                                        const float* __restrict__ b,
                                                        float* __restrict__ out) {
    __shared__ __align__(16) float lds[16384];   // 64 KB: 4x16KB stage bufs, reused as 8 zones

    const int tid  = threadIdx.x;
    const int kg   = tid >> 6;
    const int lane = tid & 63;
    const int t0   = blockIdx.x * TB;
    const int m    = lane & 31;        // token row within tile (frag row)
    const int ko   = lane >> 5;        // k-octet half

    const float* xbase = x + (size_t)t0 * DIM;
    const _Float16* wpl = wp + lane * 8;

    f32x16 acc0, acc1;
    #pragma unroll
    for (int i = 0; i < 16; ++i) { acc0[i] = 0.0f; acc1[i] = 0.0f; }

    f16x8 bs[2][4];

    // swizzled ds_read byte offsets within a 16KB buffer (constant across steps)
    const int gq  = kg * 4 + ko * 2;
    const int ro0 = m * 512 + (((gq + 0) ^ (m & 7)) << 4);
    const int ro1 = m * 512 + (((gq + 1) ^ (m & 7)) << 4);

    // stage step S: wave kg stages rows 4kg..4kg+3 (2 instrs, 2 rows = 1KB each)
#define STAGE(S) do {                                                            \
        _Pragma("unroll")                                                        \
        for (int i_ = 0; i_ < 2; ++i_) {                                         \
            const int rp_ = 4 * kg + 2 * i_;                                     \
            const int r_  = rp_ + (lane >> 5);                                   \
            const int sg_ = (lane & 31) ^ (r_ & 7);                              \
            const float* src_ = xbase + (size_t)r_ * DIM + (S) * BK + (sg_ << 2);\
            float* dst_ = lds + ((S) & 3) * 4096 + rp_ * 128;                    \
            __builtin_amdgcn_global_load_lds(                                    \
                (const __attribute__((address_space(1))) void*)src_,             \
                (__attribute__((address_space(3))) void*)dst_, 16, 0, 0);        \
        } } while (0)

    // wp fragment loads for step S (chunk C = S*8+kg), double-buffered by parity
#define WLD(S) do {                                                              \
        const _Float16* wb_ = wpl + (size_t)((S) * 8 + kg) * 2048;               \
        bs[(S) & 1][0] = *(const f16x8*)(wb_);                                   \
        bs[(S) & 1][1] = *(const f16x8*)(wb_ + 512);                             \
        bs[(S) & 1][2] = *(const f16x8*)(wb_ + 1024);                            \
        bs[(S) & 1][3] = *(const f16x8*)(wb_ + 1536);                            \
    } while (0)

    // compute step S: 1 chunk = split-f16 convert + 6 MFMAs
#define COMP(S) do {                                                             \
        const char* lb_ = (const char*)lds + ((S) & 3) * 16384;                  \
        float4 xv0_ = *(const float4*)(lb_ + ro0);                               \
        float4 xv1_ = *(const float4*)(lb_ + ro1);                               \
        f16x8 ah_, al_;                                                          \
        const float* p0_ = (const float*)&xv0_;                                  \
        const float* p1_ = (const float*)&xv1_;                                  \
        _Pragma("unroll")                                                        \
        for (int j_ = 0; j_ < 4; ++j_) {                                         \
            _Float16 h1_ = (_Float16)p0_[j_];                                    \
            ah_[j_] = h1_; al_[j_] = (_Float16)(p0_[j_] - (float)h1_);           \
            _Float16 h2_ = (_Float16)p1_[j_];                                    \
            ah_[4 + j_] = h2_; al_[4 + j_] = (_Float16)(p1_[j_] - (float)h2_);   \
        }                                                                        \
        acc0 = __builtin_amdgcn_mfma_f32_32x32x16_f16(ah_, bs[(S)&1][0], acc0, 0, 0, 0); \
        acc1 = __builtin_amdgcn_mfma_f32_32x32x16_f16(ah_, bs[(S)&1][2], acc1, 0, 0, 0); \
        acc0 = __builtin_amdgcn_mfma_f32_32x32x16_f16(ah_, bs[(S)&1][1], acc0, 0, 0, 0); \
        acc1 = __builtin_amdgcn_mfma_f32_32x32x16_f16(ah_, bs[(S)&1][3], acc1, 0, 0, 0); \
        acc0 = __builtin_amdgcn_mfma_f32_32x32x16_f16(al_, bs[(S)&1][0], acc0, 0, 0, 0); \
        acc1 = __builtin_amdgcn_mfma_f32_32x32x16_f16(al_, bs[(S)&1][2], acc1, 0, 0, 0); \
    } while (0)

    // step: issue next-chunk wp loads + stage(s+3), compute s, counted wait + barrier
#define STEP(S, VMC) do {                                                        \
        WLD((S) + 1);                                                            \
        if ((S) + 3 < NSTEP) STAGE((S) + 3);                                     \
        COMP(S);                                                                 \
        asm volatile("s_waitcnt vmcnt(" VMC ")" ::: "memory");                   \
        __builtin_amdgcn_s_barrier();                                            \
    } while (0)

    // ---- prologue: order pinned so vmcnt(8) waits exactly for stage(0) ----
    STAGE(0);
    asm volatile("" ::: "memory");
    WLD(0);
    asm volatile("" ::: "memory");
    STAGE(1);
    STAGE(2);
    asm volatile("s_waitcnt vmcnt(8)" ::: "memory");   // st0 done; wld0+st1+st2 in flight
    __builtin_amdgcn_s_barrier();

    // ---- main loop, fully unrolled: counted vmcnt keeps 3 stage-steps in flight ----
    STEP(0, "8");  STEP(1, "8");  STEP(2, "8");  STEP(3, "8");
    STEP(4, "8");  STEP(5, "8");  STEP(6, "8");  STEP(7, "8");
    STEP(8, "8");  STEP(9, "8");  STEP(10, "8"); STEP(11, "8");
    STEP(12, "8");
    STEP(13, "6");                 // no stage(16): only stage(15)+wld(14) remain
    STEP(14, "4");                 // only wld(15) remains
    COMP(15);
    __syncthreads();               // full drain before LDS overlay

#undef STEP
#undef COMP
#undef WLD
#undef STAGE

    // ---- partials -> LDS zone kg (row-major 32 x 64); overlays stage buffers ----
    float* zone = lds + kg * (TB * NE);
    #pragma unroll
    for (int r = 0; r < 16; ++r) {
        const int row = (r & 3) + 8 * (r >> 2) + 4 * ko;   // C/D layout (verified)
        zone[row * 64 + m]      = acc0[r];
        zone[row * 64 + 32 + m] = acc1[r];
    }
    __syncthreads();

    // ---- block-wide reduce of 8 zones + bias; logits to global; stage for top-2 ----
    float* logits_out = out + (size_t)TOKENS * 4;
    {
        const int row = tid >> 4;          // 0..31
        const int c4  = (tid & 15) * 4;    // col start (one float4 per thread)
        const int base = row * 64 + c4;
        float4 s0 = *(float4*)&lds[base];
        #pragma unroll
        for (int z = 1; z < KG; ++z) {
            float4 a0 = *(float4*)&lds[z * 2048 + base];
            s0.x += a0.x; s0.y += a0.y; s0.z += a0.z; s0.w += a0.w;
        }
        float4 bv0 = *(const float4*)&b[c4];
        s0.x += bv0.x; s0.y += bv0.y; s0.z += bv0.z; s0.w += bv0.w;
        *(float4*)&lds[base] = s0;     // zone0 in-place (safe: same thread's slot)
        *(float4*)&logits_out[(size_t)(t0 + row) * 64 + c4] = s0;
    }
    __syncthreads();

    // ---- top-2 + softmax: wave kg handles tokens kg*4 .. kg*4+3 ----
    float* idxf = out + (size_t)TOKENS * 2;
    for (int i = 0; i < 4; ++i) {
        const int t = kg * 4 + i;
        const float v = lds[t * 64 + lane];

        float v1 = v; int i1 = lane;
        #pragma unroll
        for (int off = 32; off >= 1; off >>= 1) {
            float ov = __shfl_xor(v1, off, 64);
            int   oi = __shfl_xor(i1, off, 64);
            if (ov > v1 || (ov == v1 && oi < i1)) { v1 = ov; i1 = oi; }
        }
        float vm = (lane == i1) ? -INFINITY : v;
        float v2 = vm; int i2 = lane;
        #pragma unroll
        for (int off = 32; off >= 1; off >>= 1) {
            float ov = __shfl_xor(v2, off, 64);
            int   oi = __shfl_xor(i2, off, 64);
            if (ov > v2 || (ov == v2 && oi < i2)) { v2 = ov; i2 = oi; }
        }

        if (lane == 0) {
            const int tok = t0 + t;
            float e1 = expf(v2 - v1);          // v1 >= v2: stable
            float sden = 1.0f + e1;
            *(float2*)&out[(size_t)tok * 2]  = make_float2(1.0f / sden, e1 / sden);
            *(float2*)&idxf[(size_t)tok * 2] = make_float2((float)i1, (float)i2);
        }
    }
}

extern "C" void kernel_launch(void* const* d_in, const int* in_sizes, int n_in,
                              void* d_out, int out_size, void* d_ws, size_t ws_size,
                              hipStream_t stream) {
    const float* x = (const float*)d_in[0];
    const float* W = (const float*)d_in[1];
    const float* b = (const float*)d_in[2];
    float* out = (float*)d_out;
    _Float16* wp = (_Float16*)d_ws;    // 128*2*2*512 f16 = 512 KB packed fragments

    wpack_kernel<<<64, 256, 0, stream>>>(W, wp);
    router_kernel<<<TOKENS / TB, 512, 0, stream>>>(x, wp, b, out);
}

// Round 7
// 198.809 us; speedup vs baseline: 1.0640x; 1.0012x over previous
//
#include <hip/hip_runtime.h>
#include <math.h>

#define TOKENS 16384
#define DIM    2048
#define NE     64
#define TB     32            // tokens per block (one 32-row MFMA tile)
#define KG     8             // k-split across the block's 8 waves
#define BK     128           // k staged per step (32 rows x 128 f32 = 16 KB buffer)
#define NSTEP  (DIM / BK)    // 16 steps; per wave per step: 1 chunk of 16 k

typedef _Float16 f16x8 __attribute__((ext_vector_type(8)));
typedef float    f32x16 __attribute__((ext_vector_type(16)));

// ---------- Kernel A: pack W fp32 -> split-f16 B-fragment layout ----------
// wp layout (f16 units): ((c*2 + eg)*2 + hl)*512 + lane*8 + j
//   c   = k-chunk (16 k), 0..127      eg = expert half (32 experts)
//   hl  = 0 hi / 1 lo residual        lane: e = eg*32+(lane&31), k = c*16+(lane>>5)*8+j
__global__ __launch_bounds__(256) void wpack_kernel(const float* __restrict__ W,
                                                    _Float16* __restrict__ wp) {
    const int g  = blockIdx.x * 256 + threadIdx.x;   // 16384 threads
    const int c  = g >> 7;
    const int eg = (g >> 6) & 1;
    const int l  = g & 63;
    const int e  = eg * 32 + (l & 31);
    const int k0 = c * 16 + (l >> 5) * 8;
    const float* src = W + (size_t)e * DIM + k0;
    float4 a = *(const float4*)src;
    float4 bq = *(const float4*)(src + 4);
    const float* pa = (const float*)&a;
    const float* pb = (const float*)&bq;
    f16x8 h, lo;
    #pragma unroll
    for (int j = 0; j < 4; ++j) {
        _Float16 h1 = (_Float16)pa[j];
        h[j] = h1; lo[j] = (_Float16)(pa[j] - (float)h1);
        _Float16 h2 = (_Float16)pb[j];
        h[4 + j] = h2; lo[4 + j] = (_Float16)(pb[j] - (float)h2);
    }
    _Float16* dst = wp + ((size_t)(c * 2 + eg) * 2) * 512 + l * 8;
    *(f16x8*)dst = h;
    *(f16x8*)(dst + 512) = lo;
}

// ---------- Kernel B: deep-pipelined LDS-staged split-f16 MFMA GEMM ----------
// k-PHASE ROTATION, compile-time-safe encoding. Theory: without rotation every
// resident block reads the SAME k-column offset simultaneously (address bits
// 8-12 identical chip-wide -> HBM channel-group hotspotting, ~50% effective BW;
// consistent with R1 occupancy-null, R2 coalescing-small, R3 pipelining-null).
// Block traverses columns (S + phase) mod 16. The mod is encoded as a phase-
// shifted base pointer + per-step UNIFORM wrap-select (s_cselect), so every
// load stays {SGPR base + compile-time immediate} exactly like verified R3 —
// avoiding 16 live runtime address chains in the unrolled body (suspected
// cause of the R4/R5 failures if they weren't pure infra).
// Structure = R3: 4 stage bufs, depth-3 prefetch, counted vmcnt, raw s_barrier,
// swizzled staging (slot = g ^ (row&7)) on both sides.
__global__ __launch_bounds__(512, 4) void router_kernel(const float* __restrict__ x,
                                                        const _Float16* __restrict__ wp,
                                                        const float* __restrict__ b,
                                                        float* __restrict__ out) {
    __shared__ __align__(16) float lds[16384];   // 64 KB: 4x16KB stage bufs, reused as 8 zones

    const int tid  = threadIdx.x;
    const int kg   = tid >> 6;
    const int lane = tid & 63;
    const int t0   = blockIdx.x * TB;
    const int m    = lane & 31;        // token row within tile (frag row)
    const int ko   = lane >> 5;        // k-octet half
    const int phase = blockIdx.x & 15; // per-block k-column rotation (SGPR-uniform)

    // phase-shifted bases; per-step wrap handled by a uniform select
    const float*    xbase = x + (size_t)t0 * DIM + phase * BK;
    const _Float16* wpl   = wp + lane * 8 + (size_t)phase * 8 * 2048;

    f32x16 acc0, acc1;
    #pragma unroll
    for (int i = 0; i < 16; ++i) { acc0[i] = 0.0f; acc1[i] = 0.0f; }

    f16x8 bs[2][4];

    // swizzled ds_read byte offsets within a 16KB buffer (constant across steps)
    const int gq  = kg * 4 + ko * 2;
    const int ro0 = m * 512 + (((gq + 0) ^ (m & 7)) << 4);
    const int ro1 = m * 512 + (((gq + 1) ^ (m & 7)) << 4);

    // stage step S: wave kg stages rows 4kg..4kg+3 (2 instrs, 2 rows = 1KB each)
    // rotated column base = xbase + S*BK, wrapped by -DIM when phase+S >= 16
#define STAGE(S) do {                                                            \
        const float* cb_ = xbase + (S) * BK - ((phase + (S) >= 16) ? DIM : 0);   \
        _Pragma("unroll")                                                        \
        for (int i_ = 0; i_ < 2; ++i_) {                                         \
            const int rp_ = 4 * kg + 2 * i_;                                     \
            const int r_  = rp_ + (lane >> 5);                                   \
            const int sg_ = (lane & 31) ^ (r_ & 7);                              \
            const float* src_ = cb_ + (size_t)r_ * DIM + (sg_ << 2);             \
            float* dst_ = lds + ((S) & 3) * 4096 + rp_ * 128;                    \
            __builtin_amdgcn_global_load_lds(                                    \
                (const __attribute__((address_space(1))) void*)src_,             \
                (__attribute__((address_space(3))) void*)dst_, 16, 0, 0);        \
        } } while (0)

    // wp fragment loads for step S: rotated chunk base, same wrap-select
#define WLD(S) do {                                                              \
        const _Float16* wb_ = wpl + (size_t)(S) * 8 * 2048 + kg * 2048           \
                              - ((phase + (S) >= 16) ? (size_t)16 * 8 * 2048 : 0);\
        bs[(S) & 1][0] = *(const f16x8*)(wb_);                                   \
        bs[(S) & 1][1] = *(const f16x8*)(wb_ + 512);                             \
        bs[(S) & 1][2] = *(const f16x8*)(wb_ + 1024);                            \
        bs[(S) & 1][3] = *(const f16x8*)(wb_ + 1536);                            \
    } while (0)

    // compute step S: 1 chunk = split-f16 convert + 6 MFMAs
#define COMP(S) do {                                                             \
        const char* lb_ = (const char*)lds + ((S) & 3) * 16384;                  \
        float4 xv0_ = *(const float4*)(lb_ + ro0);                               \
        float4 xv1_ = *(const float4*)(lb_ + ro1);                               \
        f16x8 ah_, al_;                                                          \
        const float* p0_ = (const float*)&xv0_;                                  \
        const float* p1_ = (const float*)&xv1_;                                  \
        _Pragma("unroll")                                                        \
        for (int j_ = 0; j_ < 4; ++j_) {                                         \
            _Float16 h1_ = (_Float16)p0_[j_];                                    \
            ah_[j_] = h1_; al_[j_] = (_Float16)(p0_[j_] - (float)h1_);           \
            _Float16 h2_ = (_Float16)p1_[j_];                                    \
            ah_[4 + j_] = h2_; al_[4 + j_] = (_Float16)(p1_[j_] - (float)h2_);   \
        }                                                                        \
        acc0 = __builtin_amdgcn_mfma_f32_32x32x16_f16(ah_, bs[(S)&1][0], acc0, 0, 0, 0); \
        acc1 = __builtin_amdgcn_mfma_f32_32x32x16_f16(ah_, bs[(S)&1][2], acc1, 0, 0, 0); \
        acc0 = __builtin_amdgcn_mfma_f32_32x32x16_f16(ah_, bs[(S)&1][1], acc0, 0, 0, 0); \
        acc1 = __builtin_amdgcn_mfma_f32_32x32x16_f16(ah_, bs[(S)&1][3], acc1, 0, 0, 0); \
        acc0 = __builtin_amdgcn_mfma_f32_32x32x16_f16(al_, bs[(S)&1][0], acc0, 0, 0, 0); \
        acc1 = __builtin_amdgcn_mfma_f32_32x32x16_f16(al_, bs[(S)&1][2], acc1, 0, 0, 0); \
    } while (0)

    // step: issue next-chunk wp loads + stage(s+3), compute s, counted wait + barrier
#define STEP(S, VMC) do {                                                        \
        WLD((S) + 1);                                                            \
        if ((S) + 3 < NSTEP) STAGE((S) + 3);                                     \
        COMP(S);                                                                 \
        asm volatile("s_waitcnt vmcnt(" VMC ")" ::: "memory");                   \
        __builtin_amdgcn_s_barrier();                                            \
    } while (0)

    // ---- prologue: order pinned so vmcnt(8) waits exactly for stage(0) ----
    STAGE(0);
    asm volatile("" ::: "memory");
    WLD(0);
    asm volatile("" ::: "memory");
    STAGE(1);
    STAGE(2);
    asm volatile("s_waitcnt vmcnt(8)" ::: "memory");   // st0 done; wld0+st1+st2 in flight
    __builtin_amdgcn_s_barrier();

    // ---- main loop, fully unrolled: counted vmcnt keeps 3 stage-steps in flight ----
    STEP(0, "8");  STEP(1, "8");  STEP(2, "8");  STEP(3, "8");
    STEP(4, "8");  STEP(5, "8");  STEP(6, "8");  STEP(7, "8");
    STEP(8, "8");  STEP(9, "8");  STEP(10, "8"); STEP(11, "8");
    STEP(12, "8");
    STEP(13, "6");                 // no stage(16): only stage(15)+wld(14) remain
    STEP(14, "4");                 // only wld(15) remains
    COMP(15);
    __syncthreads();               // full drain before LDS overlay

#undef STEP
#undef COMP
#undef WLD
#undef STAGE

    // ---- partials -> LDS zone kg (row-major 32 x 64); overlays stage buffers ----
    float* zone = lds + kg * (TB * NE);
    #pragma unroll
    for (int r = 0; r < 16; ++r) {
        const int row = (r & 3) + 8 * (r >> 2) + 4 * ko;   // C/D layout (verified)
        zone[row * 64 + m]      = acc0[r];
        zone[row * 64 + 32 + m] = acc1[r];
    }
    __syncthreads();

    // ---- block-wide reduce of 8 zones + bias; logits to global; stage for top-2 ----
    float* logits_out = out + (size_t)TOKENS * 4;
    {
        const int row = tid >> 4;          // 0..31
        const int c4  = (tid & 15) * 4;    // col start (one float4 per thread)
        const int base = row * 64 + c4;
        float4 s0 = *(float4*)&lds[base];
        #pragma unroll
        for (int z = 1; z < KG; ++z) {
            float4 a0 = *(float4*)&lds[z * 2048 + base];
            s0.x += a0.x; s0.y += a0.y; s0.z += a0.z; s0.w += a0.w;
        }
        float4 bv0 = *(const float4*)&b[c4];
        s0.x += bv0.x; s0.y += bv0.y; s0.z += bv0.z; s0.w += bv0.w;
        *(float4*)&lds[base] = s0;     // zone0 in-place (safe: same thread's slot)
        *(float4*)&logits_out[(size_t)(t0 + row) * 64 + c4] = s0;
    }
    __syncthreads();

    // ---- top-2 + softmax: wave kg handles tokens kg*4 .. kg*4+3 ----
    float* idxf = out + (size_t)TOKENS * 2;
    for (int i = 0; i < 4; ++i) {
        const int t = kg * 4 + i;
        const float v = lds[t * 64 + lane];

        float v1 = v; int i1 = lane;
        #pragma unroll
        for (int off = 32; off >= 1; off >>= 1) {
            float ov = __shfl_xor(v1, off, 64);
            int   oi = __shfl_xor(i1, off, 64);
            if (ov > v1 || (ov == v1 && oi < i1)) { v1 = ov; i1 = oi; }
        }
        float vm = (lane == i1) ? -INFINITY : v;
        float v2 = vm; int i2 = lane;
        #pragma unroll
        for (int off = 32; off >= 1; off >>= 1) {
            float ov = __shfl_xor(v2, off, 64);
            int   oi = __shfl_xor(i2, off, 64);
            if (ov > v2 || (ov == v2 && oi < i2)) { v2 = ov; i2 = oi; }
        }

        if (lane == 0) {
            const int tok = t0 + t;
            float e1 = expf(v2 - v1);          // v1 >= v2: stable
            float sden = 1.0f + e1;
            *(float2*)&out[(size_t)tok * 2]  = make_float2(1.0f / sden, e1 / sden);
            *(float2*)&idxf[(size_t)tok * 2] = make_float2((float)i1, (float)i2);
        }
    }
}

extern "C" void kernel_launch(void* const* d_in, const int* in_sizes, int n_in,
                              void* d_out, int out_size, void* d_ws, size_t ws_size,
                              hipStream_t stream) {
    const float* x = (const float*)d_in[0];
    const float* W = (const float*)d_in[1];
    const float* b = (const float*)d_in[2];
    float* out = (float*)d_out;
    _Float16* wp = (_Float16*)d_ws;    // 128*2*2*512 f16 = 512 KB packed fragments

    wpack_kernel<<<64, 256, 0, stream>>>(W, wp);
    router_kernel<<<TOKENS / TB, 512, 0, stream>>>(x, wp, b, out);
}